// Round 1
// 70.327 us; speedup vs baseline: 1.0128x; 1.0128x over previous
//
#include <hip/hip_runtime.h>
#include <math.h>

// CapsuleLayer routing via MFMA (u_hat never materialized):
//   logit[n,m] = in[n,:] @ cumwv[:,m]     (K=16 in bf16 MFMA, C: row=n,col=m)
//   e = exp2(logit)   (cumwv prescaled by log2 e)
//   xc[m,d] = sum_n e[n,m] in[n,d]; S[m] = sum_n e[n,m]   (E^T @ in, MFMA)
//   s = (xc/S) @ W_m (fp32 tail); v = squash(s); cumwv += W_m @ v
// C-frag(logit) == A-frag(E^T) up to an n-regroup across quads (per-wave LDS
// round-trip) [R15-verified, absmax 1.95e-3 vs 1.13e-2 threshold].
//
// R17: LDS-pipe instruction-count reduction (kernel is latency/LDS-bound;
// fills dominate the profile, kernel itself <41us):
//  - staging: thread owns 8 CONSECUTIVE rows (n0=(tid>>2)*8) with even row
//    rotation (k+2*(g&3))&7 to de-align the 256B row-block stride; inT
//    written as 16 x b32 (row-pairs packed in regs) instead of 32 x b16.
//  - cumwv stored m-major (cumT[m][d], stride 24 shorts) -> sweep B-frag is
//    ONE ds_read_b128 instead of 8 ds_read_u16.
//  - e-buffer layout psi(n)=8*(n>>2)+(n&3) (+4 upper half): C-frag side
//    writes ONE b128 per t-iter (was 2 b64); A-frag side reads 2 b64 at
//    ml*40 + (q&1)*16 + (q>>1)*4 (+8). Verified both sides for all quads.
//  - tail wv W-reads vectorized float4.
// Per-wave LDS instrs: staging 40->24, sweep 41->30 per pass.

#define TPB 1024
#define LOG2E 1.44269504088896f

typedef __attribute__((ext_vector_type(8))) short short8;   // 8 bf16 = 4 VGPR
typedef __attribute__((ext_vector_type(4))) float float4v;  // MFMA acc
typedef __attribute__((ext_vector_type(4))) unsigned uint4v;

#define DPP_ADDF(x, ctrl) \
    ((x) + __int_as_float(__builtin_amdgcn_update_dpp( \
        0, __float_as_int(x), (ctrl), 0xF, 0xF, true)))
// row_shl:4 = 0x104, row_shl:8 = 0x108

static __device__ inline unsigned short f2bf(float x) {     // RNE f32->bf16
    unsigned u = __float_as_uint(x);
    return (unsigned short)((u + 0x7FFFu + ((u >> 16) & 1u)) >> 16);
}
static __device__ inline unsigned pk2(float a, float b) {
    return (unsigned)f2bf(a) | ((unsigned)f2bf(b) << 16);
}

__global__ __launch_bounds__(TPB, 2)
void capsule_routing_kernel(const float* __restrict__ in,
                            const float* __restrict__ W,
                            float* __restrict__ out)
{
    __shared__ unsigned short innorm[2048 * 16];   // bf16 in[n][d]        64 KB
    __shared__ unsigned short inT[16 * 2056];      // bf16 in^T[d][n]+pad  64.3 KB
    __shared__ float scratch[16][320];             // per-wave multiplex   20 KB:
        // staging: colsum partials [quad*20 + d]
        // sweep:   e-buffer (632 shorts, psi-layout, ml*40 + slot)
        // reduce:  xc [m*17 + d], S at [272+ml]
    __shared__ unsigned short cumT[16 * 24];       // bf16 cumwv*LOG2E [m][d]

    const int tid  = threadIdx.x;
    const int w    = tid >> 6;       // 0..15
    const int l    = tid & 63;
    const int ml   = l & 15;         // MFMA row/col owner index
    const int quad = l >> 4;         // 0..3
    const int b    = blockIdx.x & 63;
    const int m0g  = (blockIdx.x >> 6) << 4;   // 0 or 16

    // ---- stage: fp32 dense float4 reads -> bf16 innorm + transposed inT,
    //      pass-0 column-sum partials on the fly (into scratch).
    //      Thread owns rows n0..n0+7 (consecutive), cols d0..d0+3.
    //      Even row-rotation de-aligns the 256B row-block bank stride.
    {
        const float4* gin = (const float4*)(in + ((size_t)b << 15));
        const int d0   = (tid & 3) * 4;
        const int g    = tid >> 2;          // 0..255 row-group
        const int n0   = g << 3;            // 8 rows per group
        const int rot2 = (g & 3) << 1;      // even rotation -> pairs intact
        float c0 = 0.f, c1 = 0.f, c2 = 0.f, c3 = 0.f;
        unsigned pk32[4][4];                // [col i][row-pair j], static idx
        #pragma unroll
        for (int k = 0; k < 8; ++k) {
            const int n = n0 + ((k + rot2) & 7);
            const float4 gv = gin[n * 4 + (tid & 3)];
            c0 += gv.x; c1 += gv.y; c2 += gv.z; c3 += gv.w;
            const unsigned short u0 = f2bf(gv.x), u1 = f2bf(gv.y),
                                 u2 = f2bf(gv.z), u3 = f2bf(gv.w);
            uint2 pkr; pkr.x = (unsigned)u0 | ((unsigned)u1 << 16);
                       pkr.y = (unsigned)u2 | ((unsigned)u3 << 16);
            *(uint2*)&innorm[n * 16 + d0] = pkr;          // 8B aligned
            const int j = k >> 1;
            if ((k & 1) == 0) {
                pk32[0][j] = u0; pk32[1][j] = u1;
                pk32[2][j] = u2; pk32[3][j] = u3;
            } else {
                pk32[0][j] |= (unsigned)u0 << 16; pk32[1][j] |= (unsigned)u1 << 16;
                pk32[2][j] |= (unsigned)u2 << 16; pk32[3][j] |= (unsigned)u3 << 16;
            }
        }
        #pragma unroll
        for (int j = 0; j < 4; ++j) {       // 16 x b32 inT writes (row pairs)
            const int nn = n0 + ((2 * j + rot2) & 7);     // even -> 4B aligned
            *(unsigned*)&inT[(d0 + 0) * 2056 + nn] = pk32[0][j];
            *(unsigned*)&inT[(d0 + 1) * 2056 + nn] = pk32[1][j];
            *(unsigned*)&inT[(d0 + 2) * 2056 + nn] = pk32[2][j];
            *(unsigned*)&inT[(d0 + 3) * 2056 + nn] = pk32[3][j];
        }
        // harvest colsum: lanes i,i+4,i+8,i+12 share d0 (unchanged mapping)
        c0 = DPP_ADDF(c0, 0x104); c0 = DPP_ADDF(c0, 0x108);
        c1 = DPP_ADDF(c1, 0x104); c1 = DPP_ADDF(c1, 0x108);
        c2 = DPP_ADDF(c2, 0x104); c2 = DPP_ADDF(c2, 0x108);
        c3 = DPP_ADDF(c3, 0x104); c3 = DPP_ADDF(c3, 0x108);
        if ((l & 15) < 4) {
            float4 v4; v4.x = c0; v4.y = c1; v4.z = c2; v4.w = c3;
            *(float4*)&scratch[w][quad * 20 + (l & 3) * 4] = v4;
        }
    }

    float cwv = 0.f;   // tail threads: cumulative wv[m][d=tc], fp32

    for (int pass = 0; pass < 3; ++pass) {
        // ---------- sweep (passes 1,2): MFMA chunks of 32 n ----------
        if (pass) {
            // B-frag (cumwv): B[k=d][m=ml]; one b128 from m-major cumT
            short8 bc = {0,0,0,0,0,0,0,0};
            if (quad < 2)
                bc = *(const short8*)&cumT[ml * 24 + quad * 8];  // 16B aligned
            float4v xc = {0.f, 0.f, 0.f, 0.f};
            float Sp = 0.f;
            unsigned short* ew = (unsigned short*)&scratch[w][0];  // e-buffer

            #pragma unroll 2
            for (int t = 0; t < 4; ++t) {
                const int nb = (w << 7) + (t << 5);     // wave owns 128 n
                // A-frags (in): A[n=ml][k=d]; quads 2,3 are the zero K-half
                short8 a0 = {0,0,0,0,0,0,0,0};
                short8 a1 = {0,0,0,0,0,0,0,0};
                if (quad < 2) {
                    a0 = *(const short8*)&innorm[(nb + ml) * 16 + quad * 8];
                    a1 = *(const short8*)&innorm[(nb + 16 + ml) * 16 + quad * 8];
                }
                const float4v z = {0.f, 0.f, 0.f, 0.f};
                float4v c0 = __builtin_amdgcn_mfma_f32_16x16x32_bf16(a0, bc, z, 0, 0, 0);
                float4v c1 = __builtin_amdgcn_mfma_f32_16x16x32_bf16(a1, bc, z, 0, 0, 0);
                // e = exp2(logit); C: row n = quad*4+r, col m = ml
                float e00 = exp2f(c0[0]), e01 = exp2f(c0[1]),
                      e02 = exp2f(c0[2]), e03 = exp2f(c0[3]);
                float e10 = exp2f(c1[0]), e11 = exp2f(c1[1]),
                      e12 = exp2f(c1[2]), e13 = exp2f(c1[3]);
                Sp += (e00 + e01) + (e02 + e03) + (e10 + e11) + (e12 + e13);
                // one b128 e-write, psi layout: slots 8q..8q+3 <- c0 rows,
                // 8q+4..8q+7 <- c1 rows
                uint4v ewv;
                ewv[0] = pk2(e00, e01); ewv[1] = pk2(e02, e03);
                ewv[2] = pk2(e10, e11); ewv[3] = pk2(e12, e13);
                *(uint4v*)&ew[ml * 40 + quad * 8] = ewv;    // 16B aligned
                // A-frag(E^T): e[m=ml][n_local = quad*8+j] via psi-layout
                union { uint2 u2v[2]; short8 s; } ua;
                const int ub = ml * 40 + (quad & 1) * 16 + ((quad >> 1) << 2);
                ua.u2v[0] = *(const uint2*)&ew[ub];
                ua.u2v[1] = *(const uint2*)&ew[ub + 8];
                // B-frag (in): B[k=n_local][d=ml] from transposed copy
                const short8 bi = *(const short8*)&inT[ml * 2056 + nb + quad * 8];
                xc = __builtin_amdgcn_mfma_f32_16x16x32_bf16(ua.s, bi, xc, 0, 0, 0);
            }
            // S: reduce over quads (same m = ml); e-buffer is dead now ->
            // reuse scratch[w] as the reduction slot (own wave only).
            Sp += __shfl_xor(Sp, 16);
            Sp += __shfl_xor(Sp, 32);
            #pragma unroll
            for (int r = 0; r < 4; ++r)
                scratch[w][(quad * 4 + r) * 17 + ml] = xc[r];
            if (l < 16) scratch[w][272 + l] = Sp;
        }
        __syncthreads();   // scratch slots ready (pass 0: staging + colsum)

        // ---------- tail: 4 waves, thread = (m = tid>>4, tc = tid&15) ------
        if (tid < 256) {
            const int m  = tid >> 4;
            const int tc = tid & 15;
            const int lbase = tid & 48;
            float Stot, xtot = 0.f;
            if (pass == 0) {
                Stot = 2048.f;
                #pragma unroll 4
                for (int w2 = 0; w2 < 16; ++w2)
                    #pragma unroll
                    for (int q = 0; q < 4; ++q)
                        xtot += scratch[w2][q * 20 + tc];
            } else {
                Stot = 0.f;
                #pragma unroll 4
                for (int w2 = 0; w2 < 16; ++w2) {
                    Stot += scratch[w2][272 + m];
                    xtot += scratch[w2][m * 17 + tc];
                }
            }
            // s(m,tc) = (1/S) sum_d xtot(m,d) * W[d][m0g+m][tc]  (fp32, W L2-hot)
            float s = 0.f;
            #pragma unroll
            for (int d = 0; d < 16; ++d)
                s += __shfl(xtot, lbase + d) * W[(d << 9) + ((m0g + m) << 4) + tc];
            s /= Stot;
            float n2 = s * s;
            n2 += __shfl_xor(n2, 1);
            n2 += __shfl_xor(n2, 2);
            n2 += __shfl_xor(n2, 4);
            n2 += __shfl_xor(n2, 8);
            const float nr = sqrtf(n2);
            const float v  = s * (n2 / (1.f + n2)) / (nr + 1e-7f);
            if (pass < 2) {
                // wv(m, d=tc) = sum_c W[tc][m][c] * v[c]; W row contiguous
                const float4* Wrow = (const float4*)&W[(tc << 9) + ((m0g + m) << 4)];
                float wvv = 0.f;
                #pragma unroll
                for (int c4 = 0; c4 < 4; ++c4) {
                    const float4 wf = Wrow[c4];
                    wvv += wf.x * __shfl(v, lbase + c4 * 4 + 0)
                         + wf.y * __shfl(v, lbase + c4 * 4 + 1)
                         + wf.z * __shfl(v, lbase + c4 * 4 + 2)
                         + wf.w * __shfl(v, lbase + c4 * 4 + 3);
                }
                cwv += wvv;
                cumT[m * 24 + tc] = f2bf(cwv * LOG2E);   // m-major for b128 bc
            } else {
                out[((size_t)b << 9) + ((m0g + m) << 4) + tc] = v;
            }
        }
        if (pass < 2) __syncthreads();   // cum ready; scratch free for sweep
    }
}

extern "C" void kernel_launch(void* const* d_in, const int* in_sizes, int n_in,
                              void* d_out, int out_size, void* d_ws, size_t ws_size,
                              hipStream_t stream) {
    (void)in_sizes; (void)n_in; (void)d_ws; (void)ws_size; (void)out_size;
    const float* in = (const float*)d_in[0];
    const float* W  = (const float*)d_in[1];
    float* out = (float*)d_out;
    hipLaunchKernelGGL(capsule_routing_kernel, dim3(128), dim3(TPB), 0, stream,
                       in, W, out);
}